// Round 7
// baseline (664.821 us; speedup 1.0000x reference)
//
#include <hip/hip_runtime.h>
#include <hip/hip_bf16.h>

typedef __hip_bfloat16 bf16;
typedef __bf16 bf16x8 __attribute__((ext_vector_type(8)));
typedef float f32x4 __attribute__((ext_vector_type(4)));
#define NEG_BIG (-3.0e38f)
#define SC2 0.18033688011112042f   /* 0.125 * log2(e): softmax in base-2 domain */

// All inputs and the output are FLOAT32 (per reference). Intermediates
// Q,K,V,O are bf16; GEMMs run bf16 MFMA with f32 accumulate
// (measured absmax 0.0156 << 0.069 threshold).
//
// LDS bank math (32 banks x 4B):
//  - GEMM tiles: rows of 36 ushorts = 72 B = 18 banks; gcd(18,32)=2 -> 16
//    consecutive rows cover all 16 even bank residues -> frag ds_read_b128
//    at minimum phase count. (40-ushort rows were 20 banks, gcd 4 -> 8-way.)
//  - attn tiles: rows of 68 ushorts = 136 B = 34 banks = 2 mod 32 -> same.

__device__ inline void load8_f32(const float* p, float* o) {
  float4 a = *reinterpret_cast<const float4*>(p);
  float4 b = *reinterpret_cast<const float4*>(p + 4);
  o[0]=a.x; o[1]=a.y; o[2]=a.z; o[3]=a.w;
  o[4]=b.x; o[5]=b.y; o[6]=b.z; o[7]=b.w;
}
__device__ inline unsigned short f2bf_bits(float x) {
  return __builtin_bit_cast(unsigned short, __float2bfloat16(x));
}
__device__ inline unsigned pack2bf(float lo, float hi) {
  return (unsigned)f2bf_bits(lo) | ((unsigned)f2bf_bits(hi) << 16);
}
__device__ inline bf16x8 lds8(const unsigned short* p) {
  return __builtin_bit_cast(bf16x8, *reinterpret_cast<const uint4*>(p));
}
__device__ inline f32x4 mfma16(bf16x8 a, bf16x8 b, f32x4 c) {
  return __builtin_amdgcn_mfma_f32_16x16x32_bf16(a, b, c, 0, 0, 0);
}
// chunk swizzle for B-tile transpose writes (keeps them ~2-4-way instead of
// 8-way); applied identically on write and read.
__device__ inline int bswz(int n) { return ((n >> 4) ^ (n >> 3)) & 3; }

// ---------- Kernel 1: QKV GEMM (MFMA)  X[8192,1024]f32 @ W[1024,3072]f32 + b ----------
// LDS double-buffered, ONE barrier per K-step; A prefetched 2 tiles deep,
// B 1 tile deep. bm-band XCD mapping: XCD owns 8 bm x 24 bn (bm fastest) ->
// 4 MB X-band L2-resident, W streams via L3.
__global__ __launch_bounds__(256)
void qkv_f(const float* __restrict__ X, const float* __restrict__ W,
           const float* __restrict__ bias,
           bf16* __restrict__ q, bf16* __restrict__ k, bf16* __restrict__ v)
{
  __shared__ __align__(16) unsigned short As[2][128][36];
  __shared__ __align__(16) unsigned short Bt[2][128][36];
  const int t  = threadIdx.x;
  const int wv = t >> 6, ln = t & 63;
  const int l15 = ln & 15, lg = ln >> 4;
  const int wr = wv >> 1, wc = wv & 1;

  const int id  = blockIdx.x;                    // 1536 = 8 XCD * 192
  const int xcd = id & 7, loc = id >> 3;         // loc 0..191
  const int bm  = xcd * 8 + (loc & 7);           // XCD's 8-row band, fastest
  const int bn  = loc >> 3;                      // 0..23
  const int gm0 = bm * 128, gn0 = bn * 128;

  const int arow = t >> 1, akc = (t & 1) * 16;   // A: 2 thr/row, 16 f32 each
  const int bk2  = t >> 4, bn0 = (t & 15) * 8;   // B: k-pair, 8 n each
  const int kk   = 2 * bk2;

  const f32x4 zero4 = {0.f, 0.f, 0.f, 0.f};
  f32x4 acc[4][4];
#pragma unroll
  for (int m = 0; m < 4; m++)
#pragma unroll
    for (int n = 0; n < 4; n++) acc[m][n] = zero4;

  float a0[16], a1[16], bb0[8], bb1[8];

  auto issueA = [&](int tt, float* d) {
    const float* p = X + (size_t)(gm0 + arow) * 1024 + tt * 32 + akc;
    load8_f32(p, d); load8_f32(p + 8, d + 8);
  };
  auto issueB = [&](int tt) {
    const float* p = W + (size_t)(tt * 32 + kk) * 3072 + gn0 + bn0;
    load8_f32(p, bb0); load8_f32(p + 3072, bb1);
  };
  auto cvtwrite = [&](int pb, const float* ar_) {
    unsigned short u[16];
#pragma unroll
    for (int i = 0; i < 16; i++) u[i] = f2bf_bits(ar_[i]);
    *reinterpret_cast<uint4*>(&As[pb][arow][akc])     = *reinterpret_cast<const uint4*>(u);
    *reinterpret_cast<uint4*>(&As[pb][arow][akc + 8]) = *reinterpret_cast<const uint4*>(u + 8);
#pragma unroll
    for (int j = 0; j < 8; j++) {
      const int n = bn0 + j;
      const int col = ((((kk >> 3) ^ bswz(n)) << 3) | (kk & 7));
      *reinterpret_cast<unsigned*>(&Bt[pb][n][col]) = pack2bf(bb0[j], bb1[j]);
    }
  };
  auto compute = [&](int pb) {
    bf16x8 af[4], bfr[4];
#pragma unroll
    for (int m = 0; m < 4; m++) af[m] = lds8(&As[pb][wr*64 + m*16 + l15][lg*8]);
#pragma unroll
    for (int n = 0; n < 4; n++) {
      const int nn = wc*64 + n*16 + l15;
      bfr[n] = lds8(&Bt[pb][nn][(lg ^ bswz(nn)) << 3]);
    }
#pragma unroll
    for (int n = 0; n < 4; n++)
#pragma unroll
      for (int m = 0; m < 4; m++) acc[m][n] = mfma16(af[m], bfr[n], acc[m][n]);
  };

  // prologue: buf0 <- T0; a1 <- T1 (in flight); bb <- T1 (in flight)
  issueA(0, a0); issueB(0); issueA(1, a1);
  cvtwrite(0, a0);
  issueB(1);
  __syncthreads();

#pragma unroll 1
  for (int t2 = 0; t2 < 16; t2++) {
    const int te = 2 * t2;                       // even step: compute buf0
    if (te + 2 < 32) issueA(te + 2, a0);
    compute(0);
    cvtwrite(1, a1);                             // tile te+1 -> buf1
    if (te + 2 < 32) issueB(te + 2);
    __syncthreads();
    const int to = te + 1;                       // odd step: compute buf1
    if (to + 2 < 32) issueA(to + 2, a1);
    compute(1);
    if (t2 < 15) {
      cvtwrite(0, a0);                           // tile to+1 -> buf0
      if (to + 2 < 32) issueB(to + 2);
    }
    __syncthreads();
  }

  // epilogue: scatter to Q/K/V bf16 BHSD
#pragma unroll
  for (int nf = 0; nf < 4; nf++) {
    const int base_gc = gn0 + wc*64 + nf*16;
    const int which = base_gc >> 10;
    const int h = (base_gc & 1023) >> 6;
    const int d0 = (base_gc & 63) + l15;
    const float bvs = bias[base_gc + l15];
    bf16* dst = (which == 0) ? q : ((which == 1) ? k : v);
#pragma unroll
    for (int m = 0; m < 4; m++)
#pragma unroll
      for (int ri = 0; ri < 4; ri++) {
        const int gr = gm0 + wr*64 + m*16 + lg*4 + ri;
        const int bb = gr >> 11, s = gr & 2047;
        dst[((size_t)(bb*16 + h) * 2048 + s) * 64 + d0] =
            __float2bfloat16(acc[m][nf][ri] + bvs);
      }
  }
}

// ---------- Kernel 2: causal flash attention, paired q-tiles, swapped-QK^T ----------
// Block ia handles q-tiles {ia, 31-ia}: constant 33 tile-computations/block.
// S^T = mfma(A=K, B=Q): lane owns ONE q-row (l15) with 16 k-values in regs ->
// row reductions are in-register trees + 2 shfl. PV: O^T = mfma(A=V^T, B=P^T).
__global__ __launch_bounds__(256, 4)
void attn_f(bf16* qo, const bf16* __restrict__ kg, const bf16* __restrict__ vg)
{
  __shared__ __align__(16) unsigned short Ks[64][68];
  __shared__ __align__(16) unsigned short Vt[64][68];
  __shared__ __align__(16) unsigned short Ps[4][16][68];

  const int t  = threadIdx.x;
  const int wv = t >> 6, ln = t & 63;
  const int l15 = ln & 15, lg = ln >> 4;
  const int ia = blockIdx.x, h = blockIdx.y, b = blockIdx.z;
  const int qtA = ia, qtB = 31 - ia;             // qtB > qtA always
  const size_t basebh = (size_t)(b * 16 + h) * 2048 * 64;
  const int qA0 = qtA * 64 + wv * 16;
  const int qB0 = qtB * 64 + wv * 16;

  auto loadq = [&](int q0, bf16x8* aq) {
    const bf16* qp = qo + basebh + (size_t)(q0 + l15) * 64 + lg * 8;
    uint4 u0 = *reinterpret_cast<const uint4*>(qp);
    uint4 u1 = *reinterpret_cast<const uint4*>(qp + 32);
    unsigned w[8] = {u0.x, u0.y, u0.z, u0.w, u1.x, u1.y, u1.z, u1.w};
    unsigned o[8];
#pragma unroll
    for (int i = 0; i < 8; i++) {
      float flo = __uint_as_float(w[i] << 16) * SC2;
      float fhi = __uint_as_float(w[i] & 0xffff0000u) * SC2;
      o[i] = pack2bf(flo, fhi);
    }
    aq[0] = __builtin_bit_cast(bf16x8, *reinterpret_cast<const uint4*>(o));
    aq[1] = __builtin_bit_cast(bf16x8, *reinterpret_cast<const uint4*>(o + 4));
  };
  bf16x8 aqA[2], aqB[2];
  loadq(qA0, aqA);
  loadq(qB0, aqB);

  const f32x4 zero4 = {0.f, 0.f, 0.f, 0.f};
  f32x4 accOA[4], accOB[4];                      // accO[f][r] = O[q=l15][d=f*16+lg*4+r]
  float mA = NEG_BIG, lA = 0.f, mB = NEG_BIG, lB = 0.f;
#pragma unroll
  for (int f = 0; f < 4; f++) { accOA[f] = zero4; accOB[f] = zero4; }

  const int kr = t >> 2, kc = (t & 3) * 16;      // K stage: 4 thr/row, 32B each
  const int vr = ln, vc = wv * 16;               // V stage: lane=kv row, wave=d chunk
  const bf16* kbase = kg + basebh;
  const bf16* vbase = vg + basebh;

  auto tile_compute = [&](int ct, int qt_this, const bf16x8* aq, f32x4* accO,
                          float& m_run, float& l_run) {
    f32x4 accS[4];
    __builtin_amdgcn_s_setprio(1);
#pragma unroll
    for (int f = 0; f < 4; f++) {
      bf16x8 b0 = lds8(&Ks[f*16 + l15][lg*8]);
      bf16x8 b1 = lds8(&Ks[f*16 + l15][32 + lg*8]);
      accS[f] = mfma16(b0, aq[0], zero4);        // A=K, B=Q -> S^T
      accS[f] = mfma16(b1, aq[1], accS[f]);
    }
    __builtin_amdgcn_s_setprio(0);

    float* s = reinterpret_cast<float*>(accS);   // s[f*4+r] = S[q=l15][k=f*16+lg*4+r]
    if (ct == qt_this) {                         // diagonal tile: causal mask
#pragma unroll
      for (int f = 0; f < 4; f++)
#pragma unroll
        for (int r = 0; r < 4; r++)
          if (f*16 + lg*4 + r > wv*16 + l15) s[f*4 + r] = NEG_BIG;
    }
    float t8[8];
#pragma unroll
    for (int i = 0; i < 8; i++) t8[i] = fmaxf(s[i], s[8 + i]);
    float t4a = fmaxf(t8[0], t8[4]), t4b = fmaxf(t8[1], t8[5]);
    float t4c = fmaxf(t8[2], t8[6]), t4d = fmaxf(t8[3], t8[7]);
    float mc = fmaxf(fmaxf(t4a, t4b), fmaxf(t4c, t4d));
    mc = fmaxf(mc, __shfl_xor(mc, 16));
    mc = fmaxf(mc, __shfl_xor(mc, 32));

    const float mn = fmaxf(m_run, mc);
    if (__any(mc > m_run)) {                     // defer-max: skip rescale if no growth
      const float al = exp2f(m_run - mn);
      float* ao = reinterpret_cast<float*>(accO);
#pragma unroll
      for (int i = 0; i < 16; i++) ao[i] *= al;
      l_run *= al;
    }
    m_run = mn;

    float ps = 0.f;
#pragma unroll
    for (int i = 0; i < 16; i++) { s[i] = exp2f(s[i] - mn); ps += s[i]; }
    ps += __shfl_xor(ps, 16);
    ps += __shfl_xor(ps, 32);
    l_run += ps;

#pragma unroll
    for (int f = 0; f < 4; f++)
#pragma unroll
      for (int c = 0; c < 2; c++)
        *reinterpret_cast<unsigned*>(&Ps[wv][l15][f*16 + lg*4 + 2*c]) =
            pack2bf(s[f*4 + 2*c], s[f*4 + 2*c + 1]);
    asm volatile("s_waitcnt lgkmcnt(0)" ::: "memory");
    __builtin_amdgcn_sched_barrier(0);

    bf16x8 ap0 = lds8(&Ps[wv][l15][lg*8]);       // B[k][col=l15] = P[l15][k]
    bf16x8 ap1 = lds8(&Ps[wv][l15][32 + lg*8]);
    __builtin_amdgcn_s_setprio(1);
#pragma unroll
    for (int f = 0; f < 4; f++) {
      bf16x8 bv0 = lds8(&Vt[f*16 + l15][lg*8]);
      bf16x8 bv1 = lds8(&Vt[f*16 + l15][32 + lg*8]);
      accO[f] = mfma16(bv0, ap0, accO[f]);
      accO[f] = mfma16(bv1, ap1, accO[f]);
    }
    __builtin_amdgcn_s_setprio(0);
  };

  uint4 k0 = *reinterpret_cast<const uint4*>(kbase + (size_t)kr * 64 + kc);
  uint4 k1 = *reinterpret_cast<const uint4*>(kbase + (size_t)kr * 64 + kc + 8);
  uint4 v0 = *reinterpret_cast<const uint4*>(vbase + (size_t)vr * 64 + vc);
  uint4 v1 = *reinterpret_cast<const uint4*>(vbase + (size_t)vr * 64 + vc + 8);

  for (int ct = 0; ct <= qtB; ct++) {
    *reinterpret_cast<uint4*>(&Ks[kr][kc])     = k0;
    *reinterpret_cast<uint4*>(&Ks[kr][kc + 8]) = k1;
    {
      unsigned w[8] = {v0.x, v0.y, v0.z, v0.w, v1.x, v1.y, v1.z, v1.w};
#pragma unroll
      for (int j = 0; j < 8; j++) {
        Vt[vc + 2*j][vr]     = (unsigned short)(w[j] & 0xffffu);
        Vt[vc + 2*j + 1][vr] = (unsigned short)(w[j] >> 16);
      }
    }
    __syncthreads();
    if (ct < qtB) {                              // issue next-tile loads early (T14)
      const size_t off = (size_t)(ct + 1) * 64 * 64;
      k0 = *reinterpret_cast<const uint4*>(kbase + off + (size_t)kr * 64 + kc);
      k1 = *reinterpret_cast<const uint4*>(kbase + off + (size_t)kr * 64 + kc + 8);
      v0 = *reinterpret_cast<const uint4*>(vbase + off + (size_t)vr * 64 + vc);
      v1 = *reinterpret_cast<const uint4*>(vbase + off + (size_t)vr * 64 + vc + 8);
    }
    tile_compute(ct, qtB, aqB, accOB, mB, lB);
    if (ct <= qtA) tile_compute(ct, qtA, aqA, accOA, mA, lA);
    __syncthreads();
  }

  const float invA = 1.f / lA, invB = 1.f / lB;
#pragma unroll
  for (int f = 0; f < 4; f++) {
    ushort4 sa, sb;
#pragma unroll
    for (int r = 0; r < 4; r++) {
      reinterpret_cast<unsigned short*>(&sa)[r] = f2bf_bits(accOA[f][r] * invA);
      reinterpret_cast<unsigned short*>(&sb)[r] = f2bf_bits(accOB[f][r] * invB);
    }
    *reinterpret_cast<ushort4*>(qo + basebh + (size_t)(qA0 + l15) * 64 + f*16 + lg*4) = sa;
    *reinterpret_cast<ushort4*>(qo + basebh + (size_t)(qB0 + l15) * 64 + f*16 + lg*4) = sb;
  }
}

// ---------- Kernel 3: projection (MFMA, LDS dbuf, 1 barrier/step) ----------
__global__ __launch_bounds__(256)
void proj_f(const bf16* __restrict__ A, const float* __restrict__ W,
            const float* __restrict__ bias, float* __restrict__ out)
{
  __shared__ __align__(16) unsigned short As[2][128][36];
  __shared__ __align__(16) unsigned short Bt[2][128][36];
  const int t  = threadIdx.x;
  const int wv = t >> 6, ln = t & 63;
  const int l15 = ln & 15, lg = ln >> 4;
  const int wr = wv >> 1, wc = wv & 1;

  const int id  = blockIdx.x;                    // 512 = 8 XCD * 64
  const int xcd = id & 7, loc = id >> 3;         // loc 0..63
  const int bm  = xcd * 8 + (loc & 7);           // XCD's 8-row band, fastest
  const int bn  = loc >> 3;                      // 0..7
  const int gm0 = bm * 128, gn0 = bn * 128;

  const int arow = t >> 1, akc = (t & 1) * 16;
  const int bk2  = t >> 4, bn0 = (t & 15) * 8;
  const int kk   = 2 * bk2;

  const int gr_l = gm0 + arow;
  const int bb_l = gr_l >> 11, s_l = gr_l & 2047;
  const bf16* abase = A + ((size_t)bb_l * 16 * 2048 + (size_t)s_l) * 64;  // + h*131072 + d

  const f32x4 zero4 = {0.f, 0.f, 0.f, 0.f};
  f32x4 acc[4][4];
#pragma unroll
  for (int m = 0; m < 4; m++)
#pragma unroll
    for (int n = 0; n < 4; n++) acc[m][n] = zero4;

  uint4 a0a, a0b, a1a, a1b;
  float bb0[8], bb1[8];

  auto aptr = [&](int c) {
    const int hh = c >> 6, dd = c & 63;
    return abase + (size_t)hh * 131072 + dd;
  };
  auto issueA = [&](int tt, uint4& x0, uint4& x1) {
    const bf16* ap = aptr(tt * 32 + akc);
    x0 = *reinterpret_cast<const uint4*>(ap);
    x1 = *reinterpret_cast<const uint4*>(ap + 8);
  };
  auto issueB = [&](int tt) {
    const float* p = W + (size_t)(tt * 32 + kk) * 1024 + gn0 + bn0;
    load8_f32(p, bb0); load8_f32(p + 1024, bb1);
  };
  auto wrstage = [&](int pb, const uint4& x0, const uint4& x1) {
    *reinterpret_cast<uint4*>(&As[pb][arow][akc])     = x0;
    *reinterpret_cast<uint4*>(&As[pb][arow][akc + 8]) = x1;
#pragma unroll
    for (int j = 0; j < 8; j++) {
      const int n = bn0 + j;
      const int col = ((((kk >> 3) ^ bswz(n)) << 3) | (kk & 7));
      *reinterpret_cast<unsigned*>(&Bt[pb][n][col]) = pack2bf(bb0[j], bb1[j]);
    }
  };
  auto compute = [&](int pb) {
    bf16x8 af[4], bfr[4];
#pragma unroll
    for (int m = 0; m < 4; m++) af[m] = lds8(&As[pb][wr*64 + m*16 + l15][lg*8]);
#pragma unroll
    for (int n = 0; n < 4; n++) {
      const int nn = wc*64 + n*16 + l15;
      bfr[n] = lds8(&Bt[pb][nn][(lg ^ bswz(nn)) << 3]);
    }
#pragma unroll
    for (int n = 0; n < 4; n++)
#pragma unroll
      for (int m = 0; m < 4; m++) acc[m][n] = mfma16(af[m], bfr[n], acc[m][n]);
  };

  issueA(0, a0a, a0b); issueB(0); issueA(1, a1a, a1b);
  wrstage(0, a0a, a0b);
  issueB(1);
  __syncthreads();

#pragma unroll 1
  for (int t2 = 0; t2 < 16; t2++) {
    const int te = 2 * t2;
    if (te + 2 < 32) issueA(te + 2, a0a, a0b);
    compute(0);
    wrstage(1, a1a, a1b);
    if (te + 2 < 32) issueB(te + 2);
    __syncthreads();
    const int to = te + 1;
    if (to + 2 < 32) issueA(to + 2, a1a, a1b);
    compute(1);
    if (t2 < 15) {
      wrstage(0, a0a, a0b);
      if (to + 2 < 32) issueB(to + 2);
    }
    __syncthreads();
  }

#pragma unroll
  for (int nf = 0; nf < 4; nf++) {
    const int gc = gn0 + wc*64 + nf*16 + l15;
    const float bvs = bias[gc];
#pragma unroll
    for (int m = 0; m < 4; m++)
#pragma unroll
      for (int ri = 0; ri < 4; ri++) {
        const int gr = gm0 + wr*64 + m*16 + lg*4 + ri;
        out[(size_t)gr * 1024 + gc] = acc[m][nf][ri] + bvs;
      }
  }
}

extern "C" void kernel_launch(void* const* d_in, const int* in_sizes, int n_in,
                              void* d_out, int out_size, void* d_ws, size_t ws_size,
                              hipStream_t stream)
{
  const float *x = nullptr, *W_attn = nullptr, *b_attn = nullptr,
              *W_proj = nullptr, *b_proj = nullptr;
  for (int i = 0; i < n_in; i++) {
    switch (in_sizes[i]) {
      case 8388608: x      = (const float*)d_in[i]; break;  // [4,2048,1024]
      case 3145728: W_attn = (const float*)d_in[i]; break;  // [1024,3072]
      case 3072:    b_attn = (const float*)d_in[i]; break;
      case 1048576: W_proj = (const float*)d_in[i]; break;  // [1024,1024]
      case 1024:    b_proj = (const float*)d_in[i]; break;
      default: break;
    }
  }
  if (!x || !W_attn || !b_attn || !W_proj || !b_proj) {
    x = (const float*)d_in[0]; W_attn = (const float*)d_in[1];
    b_attn = (const float*)d_in[2]; W_proj = (const float*)d_in[3];
    b_proj = (const float*)d_in[4];
  }
  float* out = (float*)d_out;        // 8388608 f32 = 32 MiB

  // Memory plan (inputs never written; ws requirement 16 MiB):
  //   Q -> ws[0:16M)  bf16 BHSD      (later overwritten block-privately by O)
  //   K -> d_out bytes [0:16M)  bf16 BHSD   } dead before proj's f32 writes
  //   V -> d_out bytes [16M:32M) bf16 BHSD  }
  const size_t NE = 8388608;         // bf16 elements per 16 MiB tensor
  bf16* qb = (bf16*)d_ws;
  bf16* kb = (bf16*)d_out;
  bf16* vb = kb + NE;

  qkv_f <<<dim3(1536), 256, 0, stream>>>(x, W_attn, b_attn, qb, kb, vb);
  attn_f<<<dim3(16, 16, 4), 256, 0, stream>>>(qb, kb, vb);
  proj_f<<<dim3(512), 256, 0, stream>>>(qb, W_proj, b_proj, out);
}

// Round 8
// 428.779 us; speedup vs baseline: 1.5505x; 1.5505x over previous
//
#include <hip/hip_runtime.h>
#include <hip/hip_bf16.h>

typedef __hip_bfloat16 bf16;
typedef __bf16 bf16x8 __attribute__((ext_vector_type(8)));
typedef float f32x4 __attribute__((ext_vector_type(4)));
#define NEG_BIG (-3.0e38f)
#define SC2 0.18033688011112042f   /* 0.125 * log2(e): softmax in base-2 domain */

// All inputs and the output are FLOAT32 (per reference). Intermediates
// Q,K,V,O are bf16; GEMMs run bf16 MFMA with f32 accumulate
// (measured absmax 0.0156 << 0.069 threshold).
//
// HARD RULE (R7 lesson): every LDS row stride must be a multiple of 16 B,
// or uint4 (ds_*_b128) accesses lose alignment and get split. GEMM B-tile
// rows: 40 ushorts = 80 B. attn rows: 72 ushorts = 144 B.
// A-operands are NOT staged in LDS: X rows (qkv) and O head-chunks (proj)
// are k-contiguous in global, so each lane loads its A-frag directly
// (removes the 8-way A-staging write conflicts and the LDS round trip).

__device__ inline void load8_f32(const float* p, float* o) {
  float4 a = *reinterpret_cast<const float4*>(p);
  float4 b = *reinterpret_cast<const float4*>(p + 4);
  o[0]=a.x; o[1]=a.y; o[2]=a.z; o[3]=a.w;
  o[4]=b.x; o[5]=b.y; o[6]=b.z; o[7]=b.w;
}
__device__ inline unsigned short f2bf_bits(float x) {
  return __builtin_bit_cast(unsigned short, __float2bfloat16(x));
}
__device__ inline unsigned pack2bf(float lo, float hi) {
  return (unsigned)f2bf_bits(lo) | ((unsigned)f2bf_bits(hi) << 16);
}
__device__ inline bf16x8 lds8(const unsigned short* p) {
  return __builtin_bit_cast(bf16x8, *reinterpret_cast<const uint4*>(p));
}
__device__ inline f32x4 mfma16(bf16x8 a, bf16x8 b, f32x4 c) {
  return __builtin_amdgcn_mfma_f32_16x16x32_bf16(a, b, c, 0, 0, 0);
}
// B-transpose chunk swizzle (write ~4-way instead of 16-way); same on read.
__device__ inline int bswz(int n) { return (n >> 4) & 3; }

// ---------- Kernel 1: QKV GEMM (MFMA)  X[8192,1024]f32 @ W[1024,3072]f32 + b ----------
// B-only LDS (single buffer, reg-prefetch 1 step). A-frags loaded directly
// from X (32 B f32 per lane per frag, cvt in regs).
__global__ __launch_bounds__(256)
void qkv_f(const float* __restrict__ X, const float* __restrict__ W,
           const float* __restrict__ bias,
           bf16* __restrict__ q, bf16* __restrict__ k, bf16* __restrict__ v)
{
  __shared__ __align__(16) unsigned short Bt[128][40];
  const int t  = threadIdx.x;
  const int wv = t >> 6, ln = t & 63;
  const int l15 = ln & 15, lg = ln >> 4;
  const int wr = wv >> 1, wc = wv & 1;

  int id = blockIdx.x;                      // 1536 = 8 * 192, XCD swizzle (R4)
  id = (id & 7) * 192 + (id >> 3);
  const int bn = id % 24, bm = id / 24;
  const int gm0 = bm * 128, gn0 = bn * 128;

  const int bk2 = t >> 4, bn0 = (t & 15) * 8;    // B: k-pair, 8 n each
  const int kk  = 2 * bk2;

  // per-lane A row pointers (k-contiguous in X)
  const float* arp[4];
#pragma unroll
  for (int m = 0; m < 4; m++)
    arp[m] = X + (size_t)(gm0 + wr*64 + m*16 + l15) * 1024 + lg * 8;

  const f32x4 zero4 = {0.f, 0.f, 0.f, 0.f};
  f32x4 acc[4][4];
#pragma unroll
  for (int m = 0; m < 4; m++)
#pragma unroll
    for (int n = 0; n < 4; n++) acc[m][n] = zero4;

  float bb0[8], bb1[8];
  auto issueB = [&](int kt) {
    const float* p = W + (size_t)(kt + kk) * 3072 + gn0 + bn0;
    load8_f32(p, bb0); load8_f32(p + 3072, bb1);
  };

  issueB(0);
  for (int kt = 0; kt < 1024; kt += 32) {
    // write B(kt) from regs (transpose, packed k-pairs, chunk swizzle)
#pragma unroll
    for (int j = 0; j < 8; j++) {
      const int n = bn0 + j;
      const int col = ((((kk >> 3) ^ bswz(n)) << 3) | (kk & 7));
      *reinterpret_cast<unsigned*>(&Bt[n][col]) = pack2bf(bb0[j], bb1[j]);
    }
    __syncthreads();
    if (kt + 32 < 1024) issueB(kt + 32);         // next B tile in flight

    // A frags direct from global + cvt
    bf16x8 af[4];
#pragma unroll
    for (int m = 0; m < 4; m++) {
      float a8[8];
      load8_f32(arp[m] + kt, a8);
      unsigned o[4];
#pragma unroll
      for (int i = 0; i < 4; i++) o[i] = pack2bf(a8[2*i], a8[2*i+1]);
      af[m] = __builtin_bit_cast(bf16x8, *reinterpret_cast<const uint4*>(o));
    }
    bf16x8 bfr[4];
#pragma unroll
    for (int n = 0; n < 4; n++) {
      const int nn = wc*64 + n*16 + l15;
      bfr[n] = lds8(&Bt[nn][(lg ^ bswz(nn)) << 3]);
    }
#pragma unroll
    for (int n = 0; n < 4; n++)
#pragma unroll
      for (int m = 0; m < 4; m++) acc[m][n] = mfma16(af[m], bfr[n], acc[m][n]);
    __syncthreads();
  }

  // epilogue: scatter to Q/K/V bf16 BHSD
#pragma unroll
  for (int nf = 0; nf < 4; nf++) {
    const int base_gc = gn0 + wc*64 + nf*16;
    const int which = base_gc >> 10;
    const int h = (base_gc & 1023) >> 6;
    const int d0 = (base_gc & 63) + l15;
    const float bvs = bias[base_gc + l15];
    bf16* dst = (which == 0) ? q : ((which == 1) ? k : v);
#pragma unroll
    for (int m = 0; m < 4; m++)
#pragma unroll
      for (int ri = 0; ri < 4; ri++) {
        const int gr = gm0 + wr*64 + m*16 + lg*4 + ri;
        const int bb = gr >> 11, s = gr & 2047;
        dst[((size_t)(bb*16 + h) * 2048 + s) * 64 + d0] =
            __float2bfloat16(acc[m][nf][ri] + bvs);
      }
  }
}

// ---------- Kernel 2: causal flash attention (R4-exact), paired q-tiles ----------
// S^T = mfma(A=K, B=Q): lane owns ONE q-row (l15) with 16 k-values in regs ->
// row reductions are in-register trees + 2 shfl. PV: O^T = mfma(A=V^T, B=P^T).
__global__ __launch_bounds__(256, 4)
void attn_f(bf16* qo, const bf16* __restrict__ kg, const bf16* __restrict__ vg)
{
  __shared__ __align__(16) unsigned short Ks[64][72];
  __shared__ __align__(16) unsigned short Vt[64][72];
  __shared__ __align__(16) unsigned short Ps[4][16][72];

  const int t  = threadIdx.x;
  const int wv = t >> 6, ln = t & 63;
  const int l15 = ln & 15, lg = ln >> 4;
  const int ia = blockIdx.x, h = blockIdx.y, b = blockIdx.z;
  const int qtA = ia, qtB = 31 - ia;             // qtB > qtA always
  const size_t basebh = (size_t)(b * 16 + h) * 2048 * 64;
  const int qA0 = qtA * 64 + wv * 16;
  const int qB0 = qtB * 64 + wv * 16;

  auto loadq = [&](int q0, bf16x8* aq) {
    const bf16* qp = qo + basebh + (size_t)(q0 + l15) * 64 + lg * 8;
    uint4 u0 = *reinterpret_cast<const uint4*>(qp);
    uint4 u1 = *reinterpret_cast<const uint4*>(qp + 32);
    unsigned w[8] = {u0.x, u0.y, u0.z, u0.w, u1.x, u1.y, u1.z, u1.w};
    unsigned o[8];
#pragma unroll
    for (int i = 0; i < 8; i++) {
      float flo = __uint_as_float(w[i] << 16) * SC2;
      float fhi = __uint_as_float(w[i] & 0xffff0000u) * SC2;
      o[i] = pack2bf(flo, fhi);
    }
    aq[0] = __builtin_bit_cast(bf16x8, *reinterpret_cast<const uint4*>(o));
    aq[1] = __builtin_bit_cast(bf16x8, *reinterpret_cast<const uint4*>(o + 4));
  };
  bf16x8 aqA[2], aqB[2];
  loadq(qA0, aqA);
  loadq(qB0, aqB);

  const f32x4 zero4 = {0.f, 0.f, 0.f, 0.f};
  f32x4 accOA[4], accOB[4];                      // accO[f][r] = O[q=l15][d=f*16+lg*4+r]
  float mA = NEG_BIG, lA = 0.f, mB = NEG_BIG, lB = 0.f;
#pragma unroll
  for (int f = 0; f < 4; f++) { accOA[f] = zero4; accOB[f] = zero4; }

  const int kr = t >> 2, kc = (t & 3) * 16;      // K stage: 4 thr/row, 32B each
  const int vr = ln, vc = wv * 16;               // V stage: lane=kv row, wave=d chunk
  const bf16* kbase = kg + basebh;
  const bf16* vbase = vg + basebh;

  auto tile_compute = [&](int ct, int qt_this, const bf16x8* aq, f32x4* accO,
                          float& m_run, float& l_run) {
    f32x4 accS[4];
    __builtin_amdgcn_s_setprio(1);
#pragma unroll
    for (int f = 0; f < 4; f++) {
      bf16x8 b0 = lds8(&Ks[f*16 + l15][lg*8]);
      bf16x8 b1 = lds8(&Ks[f*16 + l15][32 + lg*8]);
      accS[f] = mfma16(b0, aq[0], zero4);        // A=K, B=Q -> S^T
      accS[f] = mfma16(b1, aq[1], accS[f]);
    }
    __builtin_amdgcn_s_setprio(0);

    float* s = reinterpret_cast<float*>(accS);   // s[f*4+r] = S[q=l15][k=f*16+lg*4+r]
    if (ct == qt_this) {                         // diagonal tile: causal mask
#pragma unroll
      for (int f = 0; f < 4; f++)
#pragma unroll
        for (int r = 0; r < 4; r++)
          if (f*16 + lg*4 + r > wv*16 + l15) s[f*4 + r] = NEG_BIG;
    }
    float t8[8];
#pragma unroll
    for (int i = 0; i < 8; i++) t8[i] = fmaxf(s[i], s[8 + i]);
    float t4a = fmaxf(t8[0], t8[4]), t4b = fmaxf(t8[1], t8[5]);
    float t4c = fmaxf(t8[2], t8[6]), t4d = fmaxf(t8[3], t8[7]);
    float mc = fmaxf(fmaxf(t4a, t4b), fmaxf(t4c, t4d));
    mc = fmaxf(mc, __shfl_xor(mc, 16));
    mc = fmaxf(mc, __shfl_xor(mc, 32));

    const float mn = fmaxf(m_run, mc);
    if (__any(mc > m_run)) {                     // defer-max: skip rescale if no growth
      const float al = exp2f(m_run - mn);
      float* ao = reinterpret_cast<float*>(accO);
#pragma unroll
      for (int i = 0; i < 16; i++) ao[i] *= al;
      l_run *= al;
    }
    m_run = mn;

    float ps = 0.f;
#pragma unroll
    for (int i = 0; i < 16; i++) { s[i] = exp2f(s[i] - mn); ps += s[i]; }
    ps += __shfl_xor(ps, 16);
    ps += __shfl_xor(ps, 32);
    l_run += ps;

#pragma unroll
    for (int f = 0; f < 4; f++)
#pragma unroll
      for (int c = 0; c < 2; c++)
        *reinterpret_cast<unsigned*>(&Ps[wv][l15][f*16 + lg*4 + 2*c]) =
            pack2bf(s[f*4 + 2*c], s[f*4 + 2*c + 1]);
    asm volatile("s_waitcnt lgkmcnt(0)" ::: "memory");
    __builtin_amdgcn_sched_barrier(0);

    bf16x8 ap0 = lds8(&Ps[wv][l15][lg*8]);       // B[k][col=l15] = P[l15][k]
    bf16x8 ap1 = lds8(&Ps[wv][l15][32 + lg*8]);
    __builtin_amdgcn_s_setprio(1);
#pragma unroll
    for (int f = 0; f < 4; f++) {
      bf16x8 bv0 = lds8(&Vt[f*16 + l15][lg*8]);
      bf16x8 bv1 = lds8(&Vt[f*16 + l15][32 + lg*8]);
      accO[f] = mfma16(bv0, ap0, accO[f]);
      accO[f] = mfma16(bv1, ap1, accO[f]);
    }
    __builtin_amdgcn_s_setprio(0);
  };

  uint4 k0 = *reinterpret_cast<const uint4*>(kbase + (size_t)kr * 64 + kc);
  uint4 k1 = *reinterpret_cast<const uint4*>(kbase + (size_t)kr * 64 + kc + 8);
  uint4 v0 = *reinterpret_cast<const uint4*>(vbase + (size_t)vr * 64 + vc);
  uint4 v1 = *reinterpret_cast<const uint4*>(vbase + (size_t)vr * 64 + vc + 8);

  for (int ct = 0; ct <= qtB; ct++) {
    *reinterpret_cast<uint4*>(&Ks[kr][kc])     = k0;
    *reinterpret_cast<uint4*>(&Ks[kr][kc + 8]) = k1;
    {
      unsigned w[8] = {v0.x, v0.y, v0.z, v0.w, v1.x, v1.y, v1.z, v1.w};
#pragma unroll
      for (int j = 0; j < 8; j++) {
        Vt[vc + 2*j][vr]     = (unsigned short)(w[j] & 0xffffu);
        Vt[vc + 2*j + 1][vr] = (unsigned short)(w[j] >> 16);
      }
    }
    __syncthreads();
    if (ct < qtB) {                              // issue next-tile loads early (T14)
      const size_t off = (size_t)(ct + 1) * 64 * 64;
      k0 = *reinterpret_cast<const uint4*>(kbase + off + (size_t)kr * 64 + kc);
      k1 = *reinterpret_cast<const uint4*>(kbase + off + (size_t)kr * 64 + kc + 8);
      v0 = *reinterpret_cast<const uint4*>(vbase + off + (size_t)vr * 64 + vc);
      v1 = *reinterpret_cast<const uint4*>(vbase + off + (size_t)vr * 64 + vc + 8);
    }
    tile_compute(ct, qtB, aqB, accOB, mB, lB);
    if (ct <= qtA) tile_compute(ct, qtA, aqA, accOA, mA, lA);
    __syncthreads();
  }

  const float invA = 1.f / lA, invB = 1.f / lB;
#pragma unroll
  for (int f = 0; f < 4; f++) {
    ushort4 sa, sb;
#pragma unroll
    for (int r = 0; r < 4; r++) {
      reinterpret_cast<unsigned short*>(&sa)[r] = f2bf_bits(accOA[f][r] * invA);
      reinterpret_cast<unsigned short*>(&sb)[r] = f2bf_bits(accOB[f][r] * invB);
    }
    *reinterpret_cast<ushort4*>(qo + basebh + (size_t)(qA0 + l15) * 64 + f*16 + lg*4) = sa;
    *reinterpret_cast<ushort4*>(qo + basebh + (size_t)(qB0 + l15) * 64 + f*16 + lg*4) = sb;
  }
}

// ---------- Kernel 3: projection (MFMA). A (bf16 BHSD) direct-from-global ----------
__global__ __launch_bounds__(256)
void proj_f(const bf16* __restrict__ A, const float* __restrict__ W,
            const float* __restrict__ bias, float* __restrict__ out)
{
  __shared__ __align__(16) unsigned short Bt[128][40];
  const int t  = threadIdx.x;
  const int wv = t >> 6, ln = t & 63;
  const int l15 = ln & 15, lg = ln >> 4;
  const int wr = wv >> 1, wc = wv & 1;

  int id = blockIdx.x;                      // 512 = 8 * 64, XCD swizzle (R4)
  id = (id & 7) * 64 + (id >> 3);
  const int bn = id & 7, bm = id >> 3;
  const int gm0 = bm * 128, gn0 = bn * 128;

  const int bk2 = t >> 4, bn0 = (t & 15) * 8;
  const int kk  = 2 * bk2;

  // per-lane A row base (BHSD; 8-chunks stay in-head since lg*8 < 64)
  const bf16* arp[4];
#pragma unroll
  for (int m = 0; m < 4; m++) {
    const int gr = gm0 + wr*64 + m*16 + l15;
    const int bb = gr >> 11, s = gr & 2047;
    arp[m] = A + ((size_t)bb * 16 * 2048 + (size_t)s) * 64;   // + h*131072 + d
  }

  const f32x4 zero4 = {0.f, 0.f, 0.f, 0.f};
  f32x4 acc[4][4];
#pragma unroll
  for (int m = 0; m < 4; m++)
#pragma unroll
    for (int n = 0; n < 4; n++) acc[m][n] = zero4;

  float bb0[8], bb1[8];
  auto issueB = [&](int kt) {
    const float* p = W + (size_t)(kt + kk) * 1024 + gn0 + bn0;
    load8_f32(p, bb0); load8_f32(p + 1024, bb1);
  };

  issueB(0);
  for (int kt = 0; kt < 1024; kt += 32) {
#pragma unroll
    for (int j = 0; j < 8; j++) {
      const int n = bn0 + j;
      const int col = ((((kk >> 3) ^ bswz(n)) << 3) | (kk & 7));
      *reinterpret_cast<unsigned*>(&Bt[n][col]) = pack2bf(bb0[j], bb1[j]);
    }
    __syncthreads();
    if (kt + 32 < 1024) issueB(kt + 32);

    bf16x8 af[4], bfr[4];
    const int c = kt + lg*8;
    const int hh = c >> 6, dd = c & 63;
#pragma unroll
    for (int m = 0; m < 4; m++)
      af[m] = __builtin_bit_cast(bf16x8,
          *reinterpret_cast<const uint4*>(arp[m] + (size_t)hh * 131072 + dd));
#pragma unroll
    for (int n = 0; n < 4; n++) {
      const int nn = wc*64 + n*16 + l15;
      bfr[n] = lds8(&Bt[nn][(lg ^ bswz(nn)) << 3]);
    }
#pragma unroll
    for (int n = 0; n < 4; n++)
#pragma unroll
      for (int m = 0; m < 4; m++) acc[m][n] = mfma16(af[m], bfr[n], acc[m][n]);
    __syncthreads();
  }

#pragma unroll
  for (int nf = 0; nf < 4; nf++) {
    const int gc = gn0 + wc*64 + nf*16 + l15;
    const float bvs = bias[gc];
#pragma unroll
    for (int m = 0; m < 4; m++)
#pragma unroll
      for (int ri = 0; ri < 4; ri++) {
        const int gr = gm0 + wr*64 + m*16 + lg*4 + ri;
        out[(size_t)gr * 1024 + gc] = acc[m][nf][ri] + bvs;
      }
  }
}

extern "C" void kernel_launch(void* const* d_in, const int* in_sizes, int n_in,
                              void* d_out, int out_size, void* d_ws, size_t ws_size,
                              hipStream_t stream)
{
  const float *x = nullptr, *W_attn = nullptr, *b_attn = nullptr,
              *W_proj = nullptr, *b_proj = nullptr;
  for (int i = 0; i < n_in; i++) {
    switch (in_sizes[i]) {
      case 8388608: x      = (const float*)d_in[i]; break;  // [4,2048,1024]
      case 3145728: W_attn = (const float*)d_in[i]; break;  // [1024,3072]
      case 3072:    b_attn = (const float*)d_in[i]; break;
      case 1048576: W_proj = (const float*)d_in[i]; break;  // [1024,1024]
      case 1024:    b_proj = (const float*)d_in[i]; break;
      default: break;
    }
  }
  if (!x || !W_attn || !b_attn || !W_proj || !b_proj) {
    x = (const float*)d_in[0]; W_attn = (const float*)d_in[1];
    b_attn = (const float*)d_in[2]; W_proj = (const float*)d_in[3];
    b_proj = (const float*)d_in[4];
  }
  float* out = (float*)d_out;        // 8388608 f32 = 32 MiB

  // Memory plan (inputs never written; ws requirement 16 MiB):
  //   Q -> ws[0:16M)  bf16 BHSD      (later overwritten block-privately by O)
  //   K -> d_out bytes [0:16M)  bf16 BHSD   } dead before proj's f32 writes
  //   V -> d_out bytes [16M:32M) bf16 BHSD  }
  const size_t NE = 8388608;         // bf16 elements per 16 MiB tensor
  bf16* qb = (bf16*)d_ws;
  bf16* kb = (bf16*)d_out;
  bf16* vb = kb + NE;

  qkv_f <<<dim3(1536), 256, 0, stream>>>(x, W_attn, b_attn, qb, kb, vb);
  attn_f<<<dim3(16, 16, 4), 256, 0, stream>>>(qb, kb, vb);
  proj_f<<<dim3(512), 256, 0, stream>>>(qb, W_proj, b_proj, out);
}

// Round 10
// 402.541 us; speedup vs baseline: 1.6516x; 1.0652x over previous
//
#include <hip/hip_runtime.h>
#include <hip/hip_bf16.h>

typedef __hip_bfloat16 bf16;
typedef __bf16 bf16x8 __attribute__((ext_vector_type(8)));
typedef float f32x4 __attribute__((ext_vector_type(4)));
#define NEG_BIG (-3.0e38f)
#define SC2 0.18033688011112042f   /* 0.125 * log2(e): softmax in base-2 domain */

// All inputs and the output are FLOAT32 (per reference). Intermediates
// Q,K,V,O are bf16; GEMMs run bf16 MFMA with f32 accumulate
// (measured absmax 0.0156 << 0.069 threshold).
//
// qkv: A staged via global_load_lds (async DMA, 16 B/lane) into a
// double-buffered linear [128][32] f32 tile with a both-sides XOR chunk
// swizzle (DMA source col pre-swizzled by row&7; read chunk ^ row&7) ->
// 128-B rows stay bank-uniform (2 lanes/16B-slot on frag reads).
// R9 crash root-cause: prefetch column was kt*32+64 (tile skip + OOB read
// at kt=30). Fixed to (kt2+1)*32.

__device__ inline void load8_f32(const float* p, float* o) {
  float4 a = *reinterpret_cast<const float4*>(p);
  float4 b = *reinterpret_cast<const float4*>(p + 4);
  o[0]=a.x; o[1]=a.y; o[2]=a.z; o[3]=a.w;
  o[4]=b.x; o[5]=b.y; o[6]=b.z; o[7]=b.w;
}
__device__ inline unsigned short f2bf_bits(float x) {
  return __builtin_bit_cast(unsigned short, __float2bfloat16(x));
}
__device__ inline unsigned pack2bf(float lo, float hi) {
  return (unsigned)f2bf_bits(lo) | ((unsigned)f2bf_bits(hi) << 16);
}
__device__ inline bf16x8 lds8(const unsigned short* p) {
  return __builtin_bit_cast(bf16x8, *reinterpret_cast<const uint4*>(p));
}
__device__ inline f32x4 mfma16(bf16x8 a, bf16x8 b, f32x4 c) {
  return __builtin_amdgcn_mfma_f32_16x16x32_bf16(a, b, c, 0, 0, 0);
}
// B-transpose chunk swizzle (same as R4); applied identically write & read.
__device__ inline int bswz(int n) { return (n >> 4) & 3; }

// async global->LDS, 16 B per lane; LDS dest = wave-uniform base + lane*16.
#define GLDS16(gp, lp)                                                        \
  __builtin_amdgcn_global_load_lds(                                           \
      (const __attribute__((address_space(1))) void*)(gp),                    \
      (__attribute__((address_space(3))) void*)(lp), 16, 0, 0)

// ---------- Kernel 1: QKV GEMM (MFMA)  X[8192,1024]f32 @ W[1024,3072]f32 + b ----------
__global__ __launch_bounds__(256)
void qkv_f(const float* __restrict__ X, const float* __restrict__ W,
           const float* __restrict__ bias,
           bf16* __restrict__ q, bf16* __restrict__ k, bf16* __restrict__ v)
{
  __shared__ __align__(16) float AsF[2][128][32];          // 2 x 16 KB, linear
  __shared__ __align__(16) unsigned short Bt[128][40];     // 10 KB
  const int t  = threadIdx.x;
  const int wv = t >> 6, ln = t & 63;
  const int l15 = ln & 15, lg = ln >> 4;
  const int wr = wv >> 1, wc = wv & 1;

  int id = blockIdx.x;                      // 1536 = 8 * 192, XCD swizzle (R4)
  id = (id & 7) * 192 + (id >> 3);
  const int bn = id % 24, bm = id / 24;
  const int gm0 = bm * 128, gn0 = bn * 128;

  const int bk2 = t >> 4, bn0 = (t & 15) * 8;    // B: k-pair, 8 n each
  const int kk  = 2 * bk2;

  const f32x4 zero4 = {0.f, 0.f, 0.f, 0.f};
  f32x4 acc[4][4];
#pragma unroll
  for (int m = 0; m < 4; m++)
#pragma unroll
    for (int n = 0; n < 4; n++) acc[m][n] = zero4;

  // A DMA: call c covers LDS bytes (c*4+wv)*1024 + lane*16.
  // row = (c*4+wv)*8 + (ln>>3); physical chunk = ln&7 holds logical chunk
  // (ln&7)^(row&7), row&7 = ln>>3  ->  source col = ((ln&7)^(ln>>3))*4.
  const int a_r8   = ln >> 3;
  const int a_cswz = ((ln & 7) ^ a_r8) * 4;
  auto gldsA = [&](int kcol, int pb) {
#pragma unroll
    for (int c = 0; c < 4; c++) {
      const int row = (c * 4 + wv) * 8 + a_r8;
      const float* gp = X + (size_t)(gm0 + row) * 1024 + kcol + a_cswz;
      GLDS16(gp, &AsF[pb][(c * 4 + wv) * 8][0]);
    }
  };

  float bb0[8], bb1[8];
  auto issueB = [&](int kcol) {
    const float* p = W + (size_t)(kcol + kk) * 3072 + gn0 + bn0;
    load8_f32(p, bb0); load8_f32(p + 3072, bb1);
  };
  auto writeB = [&]() {
#pragma unroll
    for (int j = 0; j < 8; j++) {
      const int n = bn0 + j;
      const int col = ((((kk >> 3) ^ bswz(n)) << 3) | (kk & 7));
      *reinterpret_cast<unsigned*>(&Bt[n][col]) = pack2bf(bb0[j], bb1[j]);
    }
  };

  const int s7 = l15 & 7;                        // read-side chunk swizzle key
  auto compute = [&](int pb) {
    bf16x8 af[4], bfr[4];
#pragma unroll
    for (int m = 0; m < 4; m++) {
      const float* rowp = &AsF[pb][wr*64 + m*16 + l15][0];
      float4 x0 = *reinterpret_cast<const float4*>(rowp + (((lg*2)     ^ s7) << 2));
      float4 x1 = *reinterpret_cast<const float4*>(rowp + (((lg*2 + 1) ^ s7) << 2));
      unsigned o[4] = {pack2bf(x0.x, x0.y), pack2bf(x0.z, x0.w),
                       pack2bf(x1.x, x1.y), pack2bf(x1.z, x1.w)};
      af[m] = __builtin_bit_cast(bf16x8, *reinterpret_cast<const uint4*>(o));
    }
#pragma unroll
    for (int n = 0; n < 4; n++) {
      const int nn = wc*64 + n*16 + l15;
      bfr[n] = lds8(&Bt[nn][(lg ^ bswz(nn)) << 3]);
    }
#pragma unroll
    for (int n = 0; n < 4; n++)
#pragma unroll
      for (int m = 0; m < 4; m++) acc[m][n] = mfma16(af[m], bfr[n], acc[m][n]);
  };

  gldsA(0, 0);
  issueB(0);
#pragma unroll 1
  for (int kt2 = 0; kt2 < 32; kt2++) {
    const int pb = kt2 & 1;
    writeB();                                    // B(kt2) regs -> LDS
    __syncthreads();                             // A(kt2) DMA drained; B visible
    if (kt2 < 31) { issueB((kt2 + 1) * 32); gldsA((kt2 + 1) * 32, pb ^ 1); }
    compute(pb);
    __syncthreads();                             // Bt consumed
  }

  // epilogue: scatter to Q/K/V bf16 BHSD
#pragma unroll
  for (int nf = 0; nf < 4; nf++) {
    const int base_gc = gn0 + wc*64 + nf*16;
    const int which = base_gc >> 10;
    const int h = (base_gc & 1023) >> 6;
    const int d0 = (base_gc & 63) + l15;
    const float bvs = bias[base_gc + l15];
    bf16* dst = (which == 0) ? q : ((which == 1) ? k : v);
#pragma unroll
    for (int m = 0; m < 4; m++)
#pragma unroll
      for (int ri = 0; ri < 4; ri++) {
        const int gr = gm0 + wr*64 + m*16 + lg*4 + ri;
        const int bb = gr >> 11, s = gr & 2047;
        dst[((size_t)(bb*16 + h) * 2048 + s) * 64 + d0] =
            __float2bfloat16(acc[m][nf][ri] + bvs);
      }
  }
}

// ---------- Kernel 2: causal flash attention (R4-exact), paired q-tiles ----------
__global__ __launch_bounds__(256, 4)
void attn_f(bf16* qo, const bf16* __restrict__ kg, const bf16* __restrict__ vg)
{
  __shared__ __align__(16) unsigned short Ks[64][72];
  __shared__ __align__(16) unsigned short Vt[64][72];
  __shared__ __align__(16) unsigned short Ps[4][16][72];

  const int t  = threadIdx.x;
  const int wv = t >> 6, ln = t & 63;
  const int l15 = ln & 15, lg = ln >> 4;
  const int ia = blockIdx.x, h = blockIdx.y, b = blockIdx.z;
  const int qtA = ia, qtB = 31 - ia;             // qtB > qtA always
  const size_t basebh = (size_t)(b * 16 + h) * 2048 * 64;
  const int qA0 = qtA * 64 + wv * 16;
  const int qB0 = qtB * 64 + wv * 16;

  auto loadq = [&](int q0, bf16x8* aq) {
    const bf16* qp = qo + basebh + (size_t)(q0 + l15) * 64 + lg * 8;
    uint4 u0 = *reinterpret_cast<const uint4*>(qp);
    uint4 u1 = *reinterpret_cast<const uint4*>(qp + 32);
    unsigned w[8] = {u0.x, u0.y, u0.z, u0.w, u1.x, u1.y, u1.z, u1.w};
    unsigned o[8];
#pragma unroll
    for (int i = 0; i < 8; i++) {
      float flo = __uint_as_float(w[i] << 16) * SC2;
      float fhi = __uint_as_float(w[i] & 0xffff0000u) * SC2;
      o[i] = pack2bf(flo, fhi);
    }
    aq[0] = __builtin_bit_cast(bf16x8, *reinterpret_cast<const uint4*>(o));
    aq[1] = __builtin_bit_cast(bf16x8, *reinterpret_cast<const uint4*>(o + 4));
  };
  bf16x8 aqA[2], aqB[2];
  loadq(qA0, aqA);
  loadq(qB0, aqB);

  const f32x4 zero4 = {0.f, 0.f, 0.f, 0.f};
  f32x4 accOA[4], accOB[4];                      // accO[f][r] = O[q=l15][d=f*16+lg*4+r]
  float mA = NEG_BIG, lA = 0.f, mB = NEG_BIG, lB = 0.f;
#pragma unroll
  for (int f = 0; f < 4; f++) { accOA[f] = zero4; accOB[f] = zero4; }

  const int kr = t >> 2, kc = (t & 3) * 16;      // K stage: 4 thr/row, 32B each
  const int vr = ln, vc = wv * 16;               // V stage: lane=kv row, wave=d chunk
  const bf16* kbase = kg + basebh;
  const bf16* vbase = vg + basebh;

  auto tile_compute = [&](int ct, int qt_this, const bf16x8* aq, f32x4* accO,
                          float& m_run, float& l_run) {
    f32x4 accS[4];
    __builtin_amdgcn_s_setprio(1);
#pragma unroll
    for (int f = 0; f < 4; f++) {
      bf16x8 b0 = lds8(&Ks[f*16 + l15][lg*8]);
      bf16x8 b1 = lds8(&Ks[f*16 + l15][32 + lg*8]);
      accS[f] = mfma16(b0, aq[0], zero4);        // A=K, B=Q -> S^T
      accS[f] = mfma16(b1, aq[1], accS[f]);
    }
    __builtin_amdgcn_s_setprio(0);

    float* s = reinterpret_cast<float*>(accS);   // s[f*4+r] = S[q=l15][k=f*16+lg*4+r]
    if (ct == qt_this) {                         // diagonal tile: causal mask
#pragma unroll
      for (int f = 0; f < 4; f++)
#pragma unroll
        for (int r = 0; r < 4; r++)
          if (f*16 + lg*4 + r > wv*16 + l15) s[f*4 + r] = NEG_BIG;
    }
    float t8[8];
#pragma unroll
    for (int i = 0; i < 8; i++) t8[i] = fmaxf(s[i], s[8 + i]);
    float t4a = fmaxf(t8[0], t8[4]), t4b = fmaxf(t8[1], t8[5]);
    float t4c = fmaxf(t8[2], t8[6]), t4d = fmaxf(t8[3], t8[7]);
    float mc = fmaxf(fmaxf(t4a, t4b), fmaxf(t4c, t4d));
    mc = fmaxf(mc, __shfl_xor(mc, 16));
    mc = fmaxf(mc, __shfl_xor(mc, 32));

    const float mn = fmaxf(m_run, mc);
    if (__any(mc > m_run)) {                     // defer-max: skip rescale if no growth
      const float al = exp2f(m_run - mn);
      float* ao = reinterpret_cast<float*>(accO);
#pragma unroll
      for (int i = 0; i < 16; i++) ao[i] *= al;
      l_run *= al;
    }
    m_run = mn;

    float ps = 0.f;
#pragma unroll
    for (int i = 0; i < 16; i++) { s[i] = exp2f(s[i] - mn); ps += s[i]; }
    ps += __shfl_xor(ps, 16);
    ps += __shfl_xor(ps, 32);
    l_run += ps;

#pragma unroll
    for (int f = 0; f < 4; f++)
#pragma unroll
      for (int c = 0; c < 2; c++)
        *reinterpret_cast<unsigned*>(&Ps[wv][l15][f*16 + lg*4 + 2*c]) =
            pack2bf(s[f*4 + 2*c], s[f*4 + 2*c + 1]);
    asm volatile("s_waitcnt lgkmcnt(0)" ::: "memory");
    __builtin_amdgcn_sched_barrier(0);

    bf16x8 ap0 = lds8(&Ps[wv][l15][lg*8]);       // B[k][col=l15] = P[l15][k]
    bf16x8 ap1 = lds8(&Ps[wv][l15][32 + lg*8]);
    __builtin_amdgcn_s_setprio(1);
#pragma unroll
    for (int f = 0; f < 4; f++) {
      bf16x8 bv0 = lds8(&Vt[f*16 + l15][lg*8]);
      bf16x8 bv1 = lds8(&Vt[f*16 + l15][32 + lg*8]);
      accO[f] = mfma16(bv0, ap0, accO[f]);
      accO[f] = mfma16(bv1, ap1, accO[f]);
    }
    __builtin_amdgcn_s_setprio(0);
  };

  uint4 k0 = *reinterpret_cast<const uint4*>(kbase + (size_t)kr * 64 + kc);
  uint4 k1 = *reinterpret_cast<const uint4*>(kbase + (size_t)kr * 64 + kc + 8);
  uint4 v0 = *reinterpret_cast<const uint4*>(vbase + (size_t)vr * 64 + vc);
  uint4 v1 = *reinterpret_cast<const uint4*>(vbase + (size_t)vr * 64 + vc + 8);

  for (int ct = 0; ct <= qtB; ct++) {
    *reinterpret_cast<uint4*>(&Ks[kr][kc])     = k0;
    *reinterpret_cast<uint4*>(&Ks[kr][kc + 8]) = k1;
    {
      unsigned w[8] = {v0.x, v0.y, v0.z, v0.w, v1.x, v1.y, v1.z, v1.w};
#pragma unroll
      for (int j = 0; j < 8; j++) {
        Vt[vc + 2*j][vr]     = (unsigned short)(w[j] & 0xffffu);
        Vt[vc + 2*j + 1][vr] = (unsigned short)(w[j] >> 16);
      }
    }
    __syncthreads();
    if (ct < qtB) {                              // issue next-tile loads early (T14)
      const size_t off = (size_t)(ct + 1) * 64 * 64;
      k0 = *reinterpret_cast<const uint4*>(kbase + off + (size_t)kr * 64 + kc);
      k1 = *reinterpret_cast<const uint4*>(kbase + off + (size_t)kr * 64 + kc + 8);
      v0 = *reinterpret_cast<const uint4*>(vbase + off + (size_t)vr * 64 + vc);
      v1 = *reinterpret_cast<const uint4*>(vbase + off + (size_t)vr * 64 + vc + 8);
    }
    tile_compute(ct, qtB, aqB, accOB, mB, lB);
    if (ct <= qtA) tile_compute(ct, qtA, aqA, accOA, mA, lA);
    __syncthreads();
  }

  const float invA = 1.f / lA, invB = 1.f / lB;
#pragma unroll
  for (int f = 0; f < 4; f++) {
    ushort4 sa, sb;
#pragma unroll
    for (int r = 0; r < 4; r++) {
      reinterpret_cast<unsigned short*>(&sa)[r] = f2bf_bits(accOA[f][r] * invA);
      reinterpret_cast<unsigned short*>(&sb)[r] = f2bf_bits(accOB[f][r] * invB);
    }
    *reinterpret_cast<ushort4*>(qo + basebh + (size_t)(qA0 + l15) * 64 + f*16 + lg*4) = sa;
    *reinterpret_cast<ushort4*>(qo + basebh + (size_t)(qB0 + l15) * 64 + f*16 + lg*4) = sb;
  }
}

// ---------- Kernel 3: projection (MFMA, 2-phase pipelined — R5-exact) ----------
__global__ __launch_bounds__(256)
void proj_f(const bf16* __restrict__ A, const float* __restrict__ W,
            const float* __restrict__ bias, float* __restrict__ out)
{
  __shared__ __align__(16) unsigned short As[128][40];
  __shared__ __align__(16) unsigned short Bt[128][40];
  const int t  = threadIdx.x;
  const int wv = t >> 6, ln = t & 63;
  const int l15 = ln & 15, lg = ln >> 4;
  const int wr = wv >> 1, wc = wv & 1;

  int id = blockIdx.x;                      // 512 = 8 * 64, XCD swizzle
  id = (id & 7) * 64 + (id >> 3);
  const int bn = id & 7, bm = id >> 3;
  const int gm0 = bm * 128, gn0 = bn * 128;

  const int arow = t >> 1, akc = (t & 1) * 16;
  const int bk2  = t >> 4, bn0 = (t & 15) * 8;
  const int kk   = 2 * bk2;

  const int gr_l = gm0 + arow;
  const int bb_l = gr_l >> 11, s_l = gr_l & 2047;
  const bf16* abase = A + ((size_t)bb_l * 16 * 2048 + (size_t)s_l) * 64;  // + h*131072 + d
  const float* wrow = W + (size_t)kk * 1024 + gn0 + bn0;

  const f32x4 zero4 = {0.f, 0.f, 0.f, 0.f};
  f32x4 acc[4][4];
#pragma unroll
  for (int m = 0; m < 4; m++)
#pragma unroll
    for (int n = 0; n < 4; n++) acc[m][n] = zero4;

  auto aptr = [&](int c) {
    const int hh = c >> 6, dd = c & 63;
    return abase + (size_t)hh * 131072 + dd;
  };

  uint4 au0, au1;
  float br0[8], br1[8];
  {
    const bf16* ap = aptr(akc);
    au0 = *reinterpret_cast<const uint4*>(ap);
    au1 = *reinterpret_cast<const uint4*>(ap + 8);
    load8_f32(wrow, br0);
    load8_f32(wrow + 1024, br1);
  }

  for (int kt = 0; kt < 1024; kt += 32) {
    *reinterpret_cast<uint4*>(&As[arow][akc])     = au0;
    *reinterpret_cast<uint4*>(&As[arow][akc + 8]) = au1;
#pragma unroll
    for (int j = 0; j < 8; j++) {
      const int n = bn0 + j;
      const int col = ((((kk >> 3) ^ bswz(n)) << 3) | (kk & 7));
      *reinterpret_cast<unsigned*>(&Bt[n][col]) = pack2bf(br0[j], br1[j]);
    }
    __syncthreads();
    if (kt + 32 < 1024) {
      const bf16* ap = aptr(kt + 32 + akc);
      au0 = *reinterpret_cast<const uint4*>(ap);
      au1 = *reinterpret_cast<const uint4*>(ap + 8);
      const float* wp = wrow + (size_t)(kt + 32) * 1024;
      load8_f32(wp, br0);
      load8_f32(wp + 1024, br1);
    }
    bf16x8 af[4], bfr[4];
#pragma unroll
    for (int m = 0; m < 4; m++) af[m] = lds8(&As[wr*64 + m*16 + l15][lg*8]);
#pragma unroll
    for (int n = 0; n < 4; n++) {
      const int nn = wc*64 + n*16 + l15;
      bfr[n] = lds8(&Bt[nn][(lg ^ bswz(nn)) << 3]);
    }
#pragma unroll
    for (int n = 0; n < 4; n++)
#pragma unroll
      for (int m = 0; m < 4; m++) acc[m][n] = mfma16(af[m], bfr[n], acc[m][n]);
    __syncthreads();
  }

#pragma unroll
  for (int nf = 0; nf < 4; nf++) {
    const int gc = gn0 + wc*64 + nf*16 + l15;
    const float bvs = bias[gc];
#pragma unroll
    for (int m = 0; m < 4; m++)
#pragma unroll
      for (int ri = 0; ri < 4; ri++) {
        const int gr = gm0 + wr*64 + m*16 + lg*4 + ri;
        out[(size_t)gr * 1024 + gc] = acc[m][nf][ri] + bvs;
      }
  }
}

extern "C" void kernel_launch(void* const* d_in, const int* in_sizes, int n_in,
                              void* d_out, int out_size, void* d_ws, size_t ws_size,
                              hipStream_t stream)
{
  const float *x = nullptr, *W_attn = nullptr, *b_attn = nullptr,
              *W_proj = nullptr, *b_proj = nullptr;
  for (int i = 0; i < n_in; i++) {
    switch (in_sizes[i]) {
      case 8388608: x      = (const float*)d_in[i]; break;  // [4,2048,1024]
      case 3145728: W_attn = (const float*)d_in[i]; break;  // [1024,3072]
      case 3072:    b_attn = (const float*)d_in[i]; break;
      case 1048576: W_proj = (const float*)d_in[i]; break;  // [1024,1024]
      case 1024:    b_proj = (const float*)d_in[i]; break;
      default: break;
    }
  }
  if (!x || !W_attn || !b_attn || !W_proj || !b_proj) {
    x = (const float*)d_in[0]; W_attn = (const float*)d_in[1];
    b_attn = (const float*)d_in[2]; W_proj = (const float*)d_in[3];
    b_proj = (const float*)d_in[4];
  }
  float* out = (float*)d_out;        // 8388608 f32 = 32 MiB

  // Memory plan (inputs never written; ws requirement 16 MiB):
  //   Q -> ws[0:16M)  bf16 BHSD      (later overwritten block-privately by O)
  //   K -> d_out bytes [0:16M)  bf16 BHSD   } dead before proj's f32 writes
  //   V -> d_out bytes [16M:32M) bf16 BHSD  }
  const size_t NE = 8388608;         // bf16 elements per 16 MiB tensor
  bf16* qb = (bf16*)d_ws;
  bf16* kb = (bf16*)d_out;
  bf16* vb = kb + NE;

  qkv_f <<<dim3(1536), 256, 0, stream>>>(x, W_attn, b_attn, qb, kb, vb);
  attn_f<<<dim3(16, 16, 4), 256, 0, stream>>>(qb, kb, vb);
  proj_f<<<dim3(512), 256, 0, stream>>>(qb, W_proj, b_proj, out);
}

// Round 11
// 332.828 us; speedup vs baseline: 1.9975x; 1.2095x over previous
//
#include <hip/hip_runtime.h>
#include <hip/hip_bf16.h>

typedef __hip_bfloat16 bf16;
typedef __bf16 bf16x8 __attribute__((ext_vector_type(8)));
typedef float f32x4 __attribute__((ext_vector_type(4)));
#define NEG_BIG (-3.0e38f)
#define SC2 0.18033688011112042f   /* 0.125 * log2(e): softmax in base-2 domain */

// All inputs and the output are FLOAT32 (per reference). Intermediates
// Q,K,V,O are bf16; GEMMs run bf16 MFMA with f32 accumulate
// (measured absmax 0.0156 << 0.069 threshold).
//
// This is the verified-best configuration (measured 330.24 us): reg-dbuf
// qkv + paired-tile swapped-QK^T attn + 2-phase proj. Structural probes
// beyond it (LDS-dbuf, bank-restride, A-direct, global_load_lds DMA) all
// measured neutral-to-worse at this problem shape (see session journal
// R6-R10); the 128^2 2-barrier MFMA structure is at its shape floor.

__device__ inline void load8_f32(const float* p, float* o) {
  float4 a = *reinterpret_cast<const float4*>(p);
  float4 b = *reinterpret_cast<const float4*>(p + 4);
  o[0]=a.x; o[1]=a.y; o[2]=a.z; o[3]=a.w;
  o[4]=b.x; o[5]=b.y; o[6]=b.z; o[7]=b.w;
}
__device__ inline unsigned short f2bf_bits(float x) {
  return __builtin_bit_cast(unsigned short, __float2bfloat16(x));
}
__device__ inline unsigned pack2bf(float lo, float hi) {
  return (unsigned)f2bf_bits(lo) | ((unsigned)f2bf_bits(hi) << 16);
}
__device__ inline bf16x8 lds8(const unsigned short* p) {
  return __builtin_bit_cast(bf16x8, *reinterpret_cast<const uint4*>(p));
}
__device__ inline f32x4 mfma16(bf16x8 a, bf16x8 b, f32x4 c) {
  return __builtin_amdgcn_mfma_f32_16x16x32_bf16(a, b, c, 0, 0, 0);
}

// ---------- Kernel 1: QKV GEMM (MFMA)  X[8192,1024]f32 @ W[1024,3072]f32 + b ----------
// 2-phase pipeline: tile kt lives in regs; loop = {cvt+write LDS -> sync ->
// issue kt+32 loads (latency hides under MFMA) -> MFMA -> sync}.
__global__ __launch_bounds__(256)
void qkv_f(const float* __restrict__ X, const float* __restrict__ W,
           const float* __restrict__ bias,
           bf16* __restrict__ q, bf16* __restrict__ k, bf16* __restrict__ v)
{
  __shared__ __align__(16) unsigned short As[128][40];
  __shared__ __align__(16) unsigned short Bt[128][40];
  const int t  = threadIdx.x;
  const int wv = t >> 6, ln = t & 63;
  const int l15 = ln & 15, lg = ln >> 4;
  const int wr = wv >> 1, wc = wv & 1;

  int id = blockIdx.x;                      // 1536 = 8 * 192, XCD swizzle
  id = (id & 7) * 192 + (id >> 3);
  const int bn = id % 24, bm = id / 24;
  const int gm0 = bm * 128, gn0 = bn * 128;

  const int arow = t >> 1, akc = (t & 1) * 16;   // A: 2 thr/row, 16 f32 each
  const int bk2  = t >> 4, bn0 = (t & 15) * 8;   // B: k-pair, 8 n each
  const int kk   = 2 * bk2;

  const float* xrow = X + (size_t)(gm0 + arow) * 1024 + akc;
  const float* wrow = W + (size_t)kk * 3072 + gn0 + bn0;

  const f32x4 zero4 = {0.f, 0.f, 0.f, 0.f};
  f32x4 acc[4][4];
#pragma unroll
  for (int m = 0; m < 4; m++)
#pragma unroll
    for (int n = 0; n < 4; n++) acc[m][n] = zero4;

  float ar[16], br0[8], br1[8];
  load8_f32(xrow, ar);
  load8_f32(xrow + 8, ar + 8);
  load8_f32(wrow, br0);
  load8_f32(wrow + 3072, br1);

  for (int kt = 0; kt < 1024; kt += 32) {
    { // cvt + LDS write from staged regs
      unsigned short u[16];
#pragma unroll
      for (int i = 0; i < 16; i++) u[i] = f2bf_bits(ar[i]);
      *reinterpret_cast<uint4*>(&As[arow][akc])     = *reinterpret_cast<const uint4*>(u);
      *reinterpret_cast<uint4*>(&As[arow][akc + 8]) = *reinterpret_cast<const uint4*>(u + 8);
#pragma unroll
      for (int j = 0; j < 8; j++) {
        const int n = bn0 + j;
        const int col = ((((kk >> 3) ^ ((n >> 4) & 3)) << 3) | (kk & 7));
        *reinterpret_cast<unsigned*>(&Bt[n][col]) = pack2bf(br0[j], br1[j]);
      }
    }
    __syncthreads();
    if (kt + 32 < 1024) {                        // issue next-tile loads early
      load8_f32(xrow + kt + 32, ar);
      load8_f32(xrow + kt + 40, ar + 8);
      const float* wp = wrow + (size_t)(kt + 32) * 3072;
      load8_f32(wp, br0);
      load8_f32(wp + 3072, br1);
    }
    bf16x8 af[4], bfr[4];
#pragma unroll
    for (int m = 0; m < 4; m++) af[m] = lds8(&As[wr*64 + m*16 + l15][lg*8]);
#pragma unroll
    for (int n = 0; n < 4; n++) {
      const int nn = wc*64 + n*16 + l15;
      bfr[n] = lds8(&Bt[nn][(lg ^ ((nn >> 4) & 3)) << 3]);
    }
#pragma unroll
    for (int n = 0; n < 4; n++)
#pragma unroll
      for (int m = 0; m < 4; m++) acc[m][n] = mfma16(af[m], bfr[n], acc[m][n]);
    __syncthreads();
  }

#pragma unroll
  for (int nf = 0; nf < 4; nf++) {
    const int base_gc = gn0 + wc*64 + nf*16;
    const int which = base_gc >> 10;
    const int h = (base_gc & 1023) >> 6;
    const int d0 = (base_gc & 63) + l15;
    const float bvs = bias[base_gc + l15];
    bf16* dst = (which == 0) ? q : ((which == 1) ? k : v);
#pragma unroll
    for (int m = 0; m < 4; m++)
#pragma unroll
      for (int ri = 0; ri < 4; ri++) {
        const int gr = gm0 + wr*64 + m*16 + lg*4 + ri;
        const int bb = gr >> 11, s = gr & 2047;
        dst[((size_t)(bb*16 + h) * 2048 + s) * 64 + d0] =
            __float2bfloat16(acc[m][nf][ri] + bvs);
      }
  }
}

// ---------- Kernel 2: causal flash attention, paired q-tiles, swapped-QK^T ----------
// Block ia handles q-tiles {ia, 31-ia}: constant 33 tile-computations/block.
// S^T = mfma(A=K, B=Q): lane owns ONE q-row (l15) with 16 k-values in regs ->
// row reductions are in-register trees + 2 shfl. PV: O^T = mfma(A=V^T, B=P^T).
__global__ __launch_bounds__(256, 4)
void attn_f(bf16* qo, const bf16* __restrict__ kg, const bf16* __restrict__ vg)
{
  __shared__ __align__(16) unsigned short Ks[64][72];
  __shared__ __align__(16) unsigned short Vt[64][72];
  __shared__ __align__(16) unsigned short Ps[4][16][72];

  const int t  = threadIdx.x;
  const int wv = t >> 6, ln = t & 63;
  const int l15 = ln & 15, lg = ln >> 4;
  const int ia = blockIdx.x, h = blockIdx.y, b = blockIdx.z;
  const int qtA = ia, qtB = 31 - ia;             // qtB > qtA always
  const size_t basebh = (size_t)(b * 16 + h) * 2048 * 64;
  const int qA0 = qtA * 64 + wv * 16;
  const int qB0 = qtB * 64 + wv * 16;

  auto loadq = [&](int q0, bf16x8* aq) {
    const bf16* qp = qo + basebh + (size_t)(q0 + l15) * 64 + lg * 8;
    uint4 u0 = *reinterpret_cast<const uint4*>(qp);
    uint4 u1 = *reinterpret_cast<const uint4*>(qp + 32);
    unsigned w[8] = {u0.x, u0.y, u0.z, u0.w, u1.x, u1.y, u1.z, u1.w};
    unsigned o[8];
#pragma unroll
    for (int i = 0; i < 8; i++) {
      float flo = __uint_as_float(w[i] << 16) * SC2;
      float fhi = __uint_as_float(w[i] & 0xffff0000u) * SC2;
      o[i] = pack2bf(flo, fhi);
    }
    aq[0] = __builtin_bit_cast(bf16x8, *reinterpret_cast<const uint4*>(o));
    aq[1] = __builtin_bit_cast(bf16x8, *reinterpret_cast<const uint4*>(o + 4));
  };
  bf16x8 aqA[2], aqB[2];
  loadq(qA0, aqA);
  loadq(qB0, aqB);

  const f32x4 zero4 = {0.f, 0.f, 0.f, 0.f};
  f32x4 accOA[4], accOB[4];                      // accO[f][r] = O[q=l15][d=f*16+lg*4+r]
  float mA = NEG_BIG, lA = 0.f, mB = NEG_BIG, lB = 0.f;
#pragma unroll
  for (int f = 0; f < 4; f++) { accOA[f] = zero4; accOB[f] = zero4; }

  const int kr = t >> 2, kc = (t & 3) * 16;      // K stage: 4 thr/row, 32B each
  const int vr = ln, vc = wv * 16;               // V stage: lane=kv row, wave=d chunk
  const bf16* kbase = kg + basebh;
  const bf16* vbase = vg + basebh;

  auto tile_compute = [&](int ct, int qt_this, const bf16x8* aq, f32x4* accO,
                          float& m_run, float& l_run) {
    f32x4 accS[4];
    __builtin_amdgcn_s_setprio(1);
#pragma unroll
    for (int f = 0; f < 4; f++) {
      bf16x8 b0 = lds8(&Ks[f*16 + l15][lg*8]);
      bf16x8 b1 = lds8(&Ks[f*16 + l15][32 + lg*8]);
      accS[f] = mfma16(b0, aq[0], zero4);        // A=K, B=Q -> S^T
      accS[f] = mfma16(b1, aq[1], accS[f]);
    }
    __builtin_amdgcn_s_setprio(0);

    float* s = reinterpret_cast<float*>(accS);   // s[f*4+r] = S[q=l15][k=f*16+lg*4+r]
    if (ct == qt_this) {                         // diagonal tile: causal mask
#pragma unroll
      for (int f = 0; f < 4; f++)
#pragma unroll
        for (int r = 0; r < 4; r++)
          if (f*16 + lg*4 + r > wv*16 + l15) s[f*4 + r] = NEG_BIG;
    }
    float t8[8];
#pragma unroll
    for (int i = 0; i < 8; i++) t8[i] = fmaxf(s[i], s[8 + i]);
    float t4a = fmaxf(t8[0], t8[4]), t4b = fmaxf(t8[1], t8[5]);
    float t4c = fmaxf(t8[2], t8[6]), t4d = fmaxf(t8[3], t8[7]);
    float mc = fmaxf(fmaxf(t4a, t4b), fmaxf(t4c, t4d));
    mc = fmaxf(mc, __shfl_xor(mc, 16));
    mc = fmaxf(mc, __shfl_xor(mc, 32));

    const float mn = fmaxf(m_run, mc);
    if (__any(mc > m_run)) {                     // defer-max: skip rescale if no growth
      const float al = exp2f(m_run - mn);
      float* ao = reinterpret_cast<float*>(accO);
#pragma unroll
      for (int i = 0; i < 16; i++) ao[i] *= al;
      l_run *= al;
    }
    m_run = mn;

    float ps = 0.f;
#pragma unroll
    for (int i = 0; i < 16; i++) { s[i] = exp2f(s[i] - mn); ps += s[i]; }
    ps += __shfl_xor(ps, 16);
    ps += __shfl_xor(ps, 32);
    l_run += ps;

#pragma unroll
    for (int f = 0; f < 4; f++)
#pragma unroll
      for (int c = 0; c < 2; c++)
        *reinterpret_cast<unsigned*>(&Ps[wv][l15][f*16 + lg*4 + 2*c]) =
            pack2bf(s[f*4 + 2*c], s[f*4 + 2*c + 1]);
    asm volatile("s_waitcnt lgkmcnt(0)" ::: "memory");
    __builtin_amdgcn_sched_barrier(0);

    bf16x8 ap0 = lds8(&Ps[wv][l15][lg*8]);       // B[k][col=l15] = P[l15][k]
    bf16x8 ap1 = lds8(&Ps[wv][l15][32 + lg*8]);
    __builtin_amdgcn_s_setprio(1);
#pragma unroll
    for (int f = 0; f < 4; f++) {
      bf16x8 bv0 = lds8(&Vt[f*16 + l15][lg*8]);
      bf16x8 bv1 = lds8(&Vt[f*16 + l15][32 + lg*8]);
      accO[f] = mfma16(bv0, ap0, accO[f]);
      accO[f] = mfma16(bv1, ap1, accO[f]);
    }
    __builtin_amdgcn_s_setprio(0);
  };

  uint4 k0 = *reinterpret_cast<const uint4*>(kbase + (size_t)kr * 64 + kc);
  uint4 k1 = *reinterpret_cast<const uint4*>(kbase + (size_t)kr * 64 + kc + 8);
  uint4 v0 = *reinterpret_cast<const uint4*>(vbase + (size_t)vr * 64 + vc);
  uint4 v1 = *reinterpret_cast<const uint4*>(vbase + (size_t)vr * 64 + vc + 8);

  for (int ct = 0; ct <= qtB; ct++) {
    *reinterpret_cast<uint4*>(&Ks[kr][kc])     = k0;
    *reinterpret_cast<uint4*>(&Ks[kr][kc + 8]) = k1;
    {
      unsigned w[8] = {v0.x, v0.y, v0.z, v0.w, v1.x, v1.y, v1.z, v1.w};
#pragma unroll
      for (int j = 0; j < 8; j++) {
        Vt[vc + 2*j][vr]     = (unsigned short)(w[j] & 0xffffu);
        Vt[vc + 2*j + 1][vr] = (unsigned short)(w[j] >> 16);
      }
    }
    __syncthreads();
    if (ct < qtB) {                              // issue next-tile loads early (T14)
      const size_t off = (size_t)(ct + 1) * 64 * 64;
      k0 = *reinterpret_cast<const uint4*>(kbase + off + (size_t)kr * 64 + kc);
      k1 = *reinterpret_cast<const uint4*>(kbase + off + (size_t)kr * 64 + kc + 8);
      v0 = *reinterpret_cast<const uint4*>(vbase + off + (size_t)vr * 64 + vc);
      v1 = *reinterpret_cast<const uint4*>(vbase + off + (size_t)vr * 64 + vc + 8);
    }
    tile_compute(ct, qtB, aqB, accOB, mB, lB);
    if (ct <= qtA) tile_compute(ct, qtA, aqA, accOA, mA, lA);
    __syncthreads();
  }

  const float invA = 1.f / lA, invB = 1.f / lB;
#pragma unroll
  for (int f = 0; f < 4; f++) {
    ushort4 sa, sb;
#pragma unroll
    for (int r = 0; r < 4; r++) {
      reinterpret_cast<unsigned short*>(&sa)[r] = f2bf_bits(accOA[f][r] * invA);
      reinterpret_cast<unsigned short*>(&sb)[r] = f2bf_bits(accOB[f][r] * invB);
    }
    *reinterpret_cast<ushort4*>(qo + basebh + (size_t)(qA0 + l15) * 64 + f*16 + lg*4) = sa;
    *reinterpret_cast<ushort4*>(qo + basebh + (size_t)(qB0 + l15) * 64 + f*16 + lg*4) = sb;
  }
}

// ---------- Kernel 3: projection (MFMA, 2-phase pipelined) ----------
__global__ __launch_bounds__(256)
void proj_f(const bf16* __restrict__ A, const float* __restrict__ W,
            const float* __restrict__ bias, float* __restrict__ out)
{
  __shared__ __align__(16) unsigned short As[128][40];
  __shared__ __align__(16) unsigned short Bt[128][40];
  const int t  = threadIdx.x;
  const int wv = t >> 6, ln = t & 63;
  const int l15 = ln & 15, lg = ln >> 4;
  const int wr = wv >> 1, wc = wv & 1;

  int id = blockIdx.x;                      // 512 = 8 * 64, XCD swizzle
  id = (id & 7) * 64 + (id >> 3);
  const int bn = id & 7, bm = id >> 3;
  const int gm0 = bm * 128, gn0 = bn * 128;

  const int arow = t >> 1, akc = (t & 1) * 16;
  const int bk2  = t >> 4, bn0 = (t & 15) * 8;
  const int kk   = 2 * bk2;

  const int gr_l = gm0 + arow;
  const int bb_l = gr_l >> 11, s_l = gr_l & 2047;
  const bf16* abase = A + ((size_t)bb_l * 16 * 2048 + (size_t)s_l) * 64;  // + h*131072 + d
  const float* wrow = W + (size_t)kk * 1024 + gn0 + bn0;

  const f32x4 zero4 = {0.f, 0.f, 0.f, 0.f};
  f32x4 acc[4][4];
#pragma unroll
  for (int m = 0; m < 4; m++)
#pragma unroll
    for (int n = 0; n < 4; n++) acc[m][n] = zero4;

  auto aptr = [&](int c) {
    const int hh = c >> 6, dd = c & 63;
    return abase + (size_t)hh * 131072 + dd;
  };

  uint4 au0, au1;
  float br0[8], br1[8];
  {
    const bf16* ap = aptr(akc);
    au0 = *reinterpret_cast<const uint4*>(ap);
    au1 = *reinterpret_cast<const uint4*>(ap + 8);
    load8_f32(wrow, br0);
    load8_f32(wrow + 1024, br1);
  }

  for (int kt = 0; kt < 1024; kt += 32) {
    *reinterpret_cast<uint4*>(&As[arow][akc])     = au0;
    *reinterpret_cast<uint4*>(&As[arow][akc + 8]) = au1;
#pragma unroll
    for (int j = 0; j < 8; j++) {
      const int n = bn0 + j;
      const int col = ((((kk >> 3) ^ ((n >> 4) & 3)) << 3) | (kk & 7));
      *reinterpret_cast<unsigned*>(&Bt[n][col]) = pack2bf(br0[j], br1[j]);
    }
    __syncthreads();
    if (kt + 32 < 1024) {
      const bf16* ap = aptr(kt + 32 + akc);
      au0 = *reinterpret_cast<const uint4*>(ap);
      au1 = *reinterpret_cast<const uint4*>(ap + 8);
      const float* wp = wrow + (size_t)(kt + 32) * 1024;
      load8_f32(wp, br0);
      load8_f32(wp + 1024, br1);
    }
    bf16x8 af[4], bfr[4];
#pragma unroll
    for (int m = 0; m < 4; m++) af[m] = lds8(&As[wr*64 + m*16 + l15][lg*8]);
#pragma unroll
    for (int n = 0; n < 4; n++) {
      const int nn = wc*64 + n*16 + l15;
      bfr[n] = lds8(&Bt[nn][(lg ^ ((nn >> 4) & 3)) << 3]);
    }
#pragma unroll
    for (int n = 0; n < 4; n++)
#pragma unroll
      for (int m = 0; m < 4; m++) acc[m][n] = mfma16(af[m], bfr[n], acc[m][n]);
    __syncthreads();
  }

#pragma unroll
  for (int nf = 0; nf < 4; nf++) {
    const int gc = gn0 + wc*64 + nf*16 + l15;
    const float bvs = bias[gc];
#pragma unroll
    for (int m = 0; m < 4; m++)
#pragma unroll
      for (int ri = 0; ri < 4; ri++) {
        const int gr = gm0 + wr*64 + m*16 + lg*4 + ri;
        out[(size_t)gr * 1024 + gc] = acc[m][nf][ri] + bvs;
      }
  }
}

extern "C" void kernel_launch(void* const* d_in, const int* in_sizes, int n_in,
                              void* d_out, int out_size, void* d_ws, size_t ws_size,
                              hipStream_t stream)
{
  const float *x = nullptr, *W_attn = nullptr, *b_attn = nullptr,
              *W_proj = nullptr, *b_proj = nullptr;
  for (int i = 0; i < n_in; i++) {
    switch (in_sizes[i]) {
      case 8388608: x      = (const float*)d_in[i]; break;  // [4,2048,1024]
      case 3145728: W_attn = (const float*)d_in[i]; break;  // [1024,3072]
      case 3072:    b_attn = (const float*)d_in[i]; break;
      case 1048576: W_proj = (const float*)d_in[i]; break;  // [1024,1024]
      case 1024:    b_proj = (const float*)d_in[i]; break;
      default: break;
    }
  }
  if (!x || !W_attn || !b_attn || !W_proj || !b_proj) {
    x = (const float*)d_in[0]; W_attn = (const float*)d_in[1];
    b_attn = (const float*)d_in[2]; W_proj = (const float*)d_in[3];
    b_proj = (const float*)d_in[4];
  }
  float* out = (float*)d_out;        // 8388608 f32 = 32 MiB

  // Memory plan (inputs never written; ws requirement 16 MiB):
  //   Q -> ws[0:16M)  bf16 BHSD      (later overwritten block-privately by O)
  //   K -> d_out bytes [0:16M)  bf16 BHSD   } dead before proj's f32 writes
  //   V -> d_out bytes [16M:32M) bf16 BHSD  }
  const size_t NE = 8388608;         // bf16 elements per 16 MiB tensor
  bf16* qb = (bf16*)d_ws;
  bf16* kb = (bf16*)d_out;
  bf16* vb = kb + NE;

  qkv_f <<<dim3(1536), 256, 0, stream>>>(x, W_attn, b_attn, qb, kb, vb);
  attn_f<<<dim3(16, 16, 4), 256, 0, stream>>>(qb, kb, vb);
  proj_f<<<dim3(512), 256, 0, stream>>>(qb, W_proj, b_proj, out);
}